// Round 1
// baseline (1176.698 us; speedup 1.0000x reference)
//
#include <hip/hip_runtime.h>
#include <cstdint>
#include <cmath>

#define T_TOK 8192
#define H_DIM 1024
#define F_DIM 4096
#define NE 8
#define CAP 8192        // perm capacity per expert
#define MBLK_MAX 32     // max M-blocks per expert (4096-token cap; >50 sigma above mean 2048)

typedef __attribute__((ext_vector_type(8))) short short8v;
typedef __attribute__((ext_vector_type(4))) float f32x4;

static __device__ __forceinline__ unsigned short f2bf(float f) {
    union { float f; unsigned int u; } v; v.f = f;
    unsigned int r = v.u + 0x7FFFu + ((v.u >> 16) & 1u);  // RNE
    return (unsigned short)(r >> 16);
}

// ---------------- router: logits, top-2, weights, per-expert compaction ----------------
__global__ void router_k(const float* __restrict__ x, const float* __restrict__ Wr,
                         const float* __restrict__ br,
                         int* __restrict__ cnt, int* __restrict__ perm, float* __restrict__ pw)
{
    const int wave = threadIdx.x >> 6;
    const int lane = threadIdx.x & 63;
    const int t = blockIdx.x * 4 + wave;
    const float* xr = x + (size_t)t * H_DIM;
    float acc[NE];
#pragma unroll
    for (int e = 0; e < NE; ++e) acc[e] = 0.f;
#pragma unroll
    for (int c0 = 0; c0 < H_DIM; c0 += 256) {
        const float4 v = *(const float4*)(xr + c0 + lane * 4);
        const int hbase = c0 + lane * 4;
        float vv[4] = {v.x, v.y, v.z, v.w};
#pragma unroll
        for (int i = 0; i < 4; ++i) {
            const float4 w0 = *(const float4*)(Wr + (size_t)(hbase + i) * NE);
            const float4 w1 = *(const float4*)(Wr + (size_t)(hbase + i) * NE + 4);
            acc[0] += vv[i] * w0.x; acc[1] += vv[i] * w0.y;
            acc[2] += vv[i] * w0.z; acc[3] += vv[i] * w0.w;
            acc[4] += vv[i] * w1.x; acc[5] += vv[i] * w1.y;
            acc[6] += vv[i] * w1.z; acc[7] += vv[i] * w1.w;
        }
    }
#pragma unroll
    for (int off = 32; off > 0; off >>= 1) {
#pragma unroll
        for (int e = 0; e < NE; ++e) acc[e] += __shfl_xor(acc[e], off, 64);
    }
    if (lane == 0) {
#pragma unroll
        for (int e = 0; e < NE; ++e) acc[e] += br[e];
        int i0 = 0; float l0 = acc[0];
#pragma unroll
        for (int e = 1; e < NE; ++e) if (acc[e] > l0) { l0 = acc[e]; i0 = e; }
        int i1 = -1; float l1 = -3.4e38f;
#pragma unroll
        for (int e = 0; e < NE; ++e) if (e != i0 && acc[e] > l1) { l1 = acc[e]; i1 = e; }
        // top-2 renormalized softmax weights from logits (exact)
        const float w0 = 1.f / (1.f + expf(l1 - l0));
        const int p0 = atomicAdd(&cnt[i0], 1);
        perm[i0 * CAP + p0] = t; pw[i0 * CAP + p0] = w0;
        const int p1 = atomicAdd(&cnt[i1], 1);
        perm[i1 * CAP + p1] = t; pw[i1 * CAP + p1] = 1.f - w0;
    }
}

// ---------------- 128-aligned exclusive prefix of counts ----------------
__global__ void prefix_k(const int* __restrict__ cnt, int* __restrict__ offs)
{
    if (threadIdx.x == 0 && blockIdx.x == 0) {
        int o = 0;
        for (int e = 0; e < NE; ++e) { offs[e] = o; o += ((cnt[e] + 127) >> 7) << 7; }
        offs[NE] = o;
    }
}

// ---------------- transpose + fp32->bf16 convert: in[E][R][C] -> out[E][C][R] ----------------
__global__ __launch_bounds__(256) void tcvt_k(const float* __restrict__ in,
                                              unsigned short* __restrict__ out,
                                              int R, int C)
{
    __shared__ float tile[64][65];
    const int e = blockIdx.z;
    const int r0 = blockIdx.y * 64, c0 = blockIdx.x * 64;
    const float* ip = in + (size_t)e * R * C;
    unsigned short* op = out + (size_t)e * R * C;
    const int j = threadIdx.x;
    const int lr = j >> 4, lc = (j & 15) * 4;
#pragma unroll
    for (int p = 0; p < 4; ++p) {
        const float4 v = *(const float4*)(ip + (size_t)(r0 + lr + p * 16) * C + c0 + lc);
        tile[lr + p * 16][lc + 0] = v.x;
        tile[lr + p * 16][lc + 1] = v.y;
        tile[lr + p * 16][lc + 2] = v.z;
        tile[lr + p * 16][lc + 3] = v.w;
    }
    __syncthreads();
#pragma unroll
    for (int p = 0; p < 4; ++p) {
        const int orow = lr + p * 16;
        ushort4 o;
        o.x = f2bf(tile[lc + 0][orow]);
        o.y = f2bf(tile[lc + 1][orow]);
        o.z = f2bf(tile[lc + 2][orow]);
        o.w = f2bf(tile[lc + 3][orow]);
        *(ushort4*)(op + (size_t)(c0 + orow) * R + r0 + lc) = o;
    }
}

// ---------------- x fp32 -> bf16 ----------------
__global__ __launch_bounds__(256) void xcvt_k(const float* __restrict__ x,
                                              unsigned short* __restrict__ xb)
{
    const size_t i = ((size_t)blockIdx.x * 256 + threadIdx.x) * 8;
    const float4 a = *(const float4*)(x + i);
    const float4 b = *(const float4*)(x + i + 4);
    uint4 o;
    o.x = f2bf(a.x) | ((unsigned)f2bf(a.y) << 16);
    o.y = f2bf(a.z) | ((unsigned)f2bf(a.w) << 16);
    o.z = f2bf(b.x) | ((unsigned)f2bf(b.y) << 16);
    o.w = f2bf(b.z) | ((unsigned)f2bf(b.w) << 16);
    *(uint4*)(xb + i) = o;
}

// ---------------- GEMM1: h = gelu(gather(x) @ W1[e] + b1[e]), bf16 out ----------------
__global__ __launch_bounds__(256, 2) void gemm1_k(
    const unsigned short* __restrict__ xb,   // [T][H] bf16
    const unsigned short* __restrict__ w1t,  // [E][F][H] bf16 (pre-transposed)
    const float* __restrict__ b1,            // [E][F]
    unsigned short* __restrict__ hbuf,       // [rows][F] bf16
    const int* __restrict__ perm, const int* __restrict__ cnt, const int* __restrict__ offs)
{
    constexpr int LDK = 72;  // 64 + 8 pad (144B rows: frag reads 2-way conflict = free)
    __shared__ __align__(16) unsigned short lA[128 * LDK];
    __shared__ __align__(16) unsigned short lB[128 * LDK];
    __shared__ int rows_s[128];

    const int e = blockIdx.z;
    const int c = cnt[e];
    const int m0 = blockIdx.y * 128;
    if (m0 >= c) return;
    const int nb = blockIdx.x;
    const int tid = threadIdx.x;

    if (tid < 128) {
        const int i = m0 + tid;
        rows_s[tid] = perm[e * CAP + (i < c ? i : c - 1)];
    }
    __syncthreads();

    const unsigned short* bp = w1t + ((size_t)e * F_DIM + nb * 128) * H_DIM;

    f32x4 acc[4][4];
#pragma unroll
    for (int m = 0; m < 4; ++m)
#pragma unroll
        for (int n = 0; n < 4; ++n) acc[m][n] = (f32x4){0.f, 0.f, 0.f, 0.f};

    const int lane = tid & 63;
    const int wr = (tid >> 7) & 1;
    const int wc = (tid >> 6) & 1;
    const int fr = lane & 15;
    const int fg = lane >> 4;
    const int sr = tid >> 3;
    const int sc = tid & 7;

    for (int k0 = 0; k0 < H_DIM; k0 += 64) {
#pragma unroll
        for (int p = 0; p < 4; ++p) {
            const int r = sr + p * 32;
            const uint4 va = *(const uint4*)(xb + (size_t)rows_s[r] * H_DIM + k0 + sc * 8);
            *(uint4*)(lA + r * LDK + sc * 8) = va;
        }
#pragma unroll
        for (int p = 0; p < 4; ++p) {
            const int r = sr + p * 32;
            const uint4 vb = *(const uint4*)(bp + (size_t)r * H_DIM + k0 + sc * 8);
            *(uint4*)(lB + r * LDK + sc * 8) = vb;
        }
        __syncthreads();
#pragma unroll
        for (int kk = 0; kk < 64; kk += 32) {
            const int kb = kk + fg * 8;
            short8v a[4], b[4];
#pragma unroll
            for (int m = 0; m < 4; ++m)
                a[m] = *(const short8v*)(lA + (wr * 64 + m * 16 + fr) * LDK + kb);
#pragma unroll
            for (int n = 0; n < 4; ++n)
                b[n] = *(const short8v*)(lB + (wc * 64 + n * 16 + fr) * LDK + kb);
#pragma unroll
            for (int m = 0; m < 4; ++m)
#pragma unroll
                for (int n = 0; n < 4; ++n)
                    acc[m][n] = __builtin_amdgcn_mfma_f32_16x16x32_bf16(a[m], b[n], acc[m][n], 0, 0, 0);
        }
        __syncthreads();
    }

    const size_t hrow0 = (size_t)offs[e] + m0;
#pragma unroll
    for (int n = 0; n < 4; ++n) {
        const int gc = nb * 128 + wc * 64 + n * 16 + fr;
        const float bias = b1[e * F_DIM + gc];
#pragma unroll
        for (int m = 0; m < 4; ++m) {
#pragma unroll
            for (int r = 0; r < 4; ++r) {
                const int lr2 = wr * 64 + m * 16 + fg * 4 + r;
                const float xv = acc[m][n][r] + bias;
                const float g = 0.5f * xv * (1.f + erff(xv * 0.70710678118f));
                hbuf[(hrow0 + lr2) * F_DIM + gc] = f2bf(g);
            }
        }
    }
}

// ---------------- GEMM2: out[t] += w * (h @ W2[e] + b2[e]) ----------------
__global__ __launch_bounds__(256, 2) void gemm2_k(
    const unsigned short* __restrict__ hbuf, // [rows][F] bf16
    const unsigned short* __restrict__ w2t,  // [E][H][F] bf16 (pre-transposed)
    const float* __restrict__ b2,            // [E][H]
    float* __restrict__ out,                 // [T][H] fp32 (pre-zeroed)
    const int* __restrict__ perm, const float* __restrict__ pw,
    const int* __restrict__ cnt, const int* __restrict__ offs)
{
    constexpr int LDK = 72;
    __shared__ __align__(16) unsigned short lA[128 * LDK];
    __shared__ __align__(16) unsigned short lB[128 * LDK];
    __shared__ int rows_s[128];
    __shared__ float pw_s[128];

    const int e = blockIdx.z;
    const int c = cnt[e];
    const int m0 = blockIdx.y * 128;
    if (m0 >= c) return;
    const int nb = blockIdx.x;
    const int tid = threadIdx.x;

    if (tid < 128) {
        const int i = m0 + tid;
        const int ic = (i < c ? i : c - 1);
        rows_s[tid] = perm[e * CAP + ic];
        pw_s[tid]   = pw[e * CAP + ic];
    }
    __syncthreads();

    const size_t arow0 = (size_t)offs[e] + m0;
    const unsigned short* bp = w2t + ((size_t)e * H_DIM + nb * 128) * F_DIM;

    f32x4 acc[4][4];
#pragma unroll
    for (int m = 0; m < 4; ++m)
#pragma unroll
        for (int n = 0; n < 4; ++n) acc[m][n] = (f32x4){0.f, 0.f, 0.f, 0.f};

    const int lane = tid & 63;
    const int wr = (tid >> 7) & 1;
    const int wc = (tid >> 6) & 1;
    const int fr = lane & 15;
    const int fg = lane >> 4;
    const int sr = tid >> 3;
    const int sc = tid & 7;

    for (int k0 = 0; k0 < F_DIM; k0 += 64) {
#pragma unroll
        for (int p = 0; p < 4; ++p) {
            const int r = sr + p * 32;
            const uint4 va = *(const uint4*)(hbuf + (arow0 + r) * F_DIM + k0 + sc * 8);
            *(uint4*)(lA + r * LDK + sc * 8) = va;
        }
#pragma unroll
        for (int p = 0; p < 4; ++p) {
            const int r = sr + p * 32;
            const uint4 vb = *(const uint4*)(bp + (size_t)r * F_DIM + k0 + sc * 8);
            *(uint4*)(lB + r * LDK + sc * 8) = vb;
        }
        __syncthreads();
#pragma unroll
        for (int kk = 0; kk < 64; kk += 32) {
            const int kb = kk + fg * 8;
            short8v a[4], b[4];
#pragma unroll
            for (int m = 0; m < 4; ++m)
                a[m] = *(const short8v*)(lA + (wr * 64 + m * 16 + fr) * LDK + kb);
#pragma unroll
            for (int n = 0; n < 4; ++n)
                b[n] = *(const short8v*)(lB + (wc * 64 + n * 16 + fr) * LDK + kb);
#pragma unroll
            for (int m = 0; m < 4; ++m)
#pragma unroll
                for (int n = 0; n < 4; ++n)
                    acc[m][n] = __builtin_amdgcn_mfma_f32_16x16x32_bf16(a[m], b[n], acc[m][n], 0, 0, 0);
        }
        __syncthreads();
    }

#pragma unroll
    for (int n = 0; n < 4; ++n) {
        const int gc = nb * 128 + wc * 64 + n * 16 + fr;
        const float bias = b2[e * H_DIM + gc];
#pragma unroll
        for (int m = 0; m < 4; ++m) {
#pragma unroll
            for (int r = 0; r < 4; ++r) {
                const int lr2 = wr * 64 + m * 16 + fg * 4 + r;
                if (m0 + lr2 < c) {
                    const float y = acc[m][n][r] + bias;
                    atomicAdd(out + (size_t)rows_s[lr2] * H_DIM + gc, pw_s[lr2] * y);
                }
            }
        }
    }
}

extern "C" void kernel_launch(void* const* d_in, const int* in_sizes, int n_in,
                              void* d_out, int out_size, void* d_ws, size_t ws_size,
                              hipStream_t stream)
{
    const float* x  = (const float*)d_in[0];
    const float* Wr = (const float*)d_in[1];
    const float* br = (const float*)d_in[2];
    const float* W1 = (const float*)d_in[3];
    const float* b1 = (const float*)d_in[4];
    const float* W2 = (const float*)d_in[5];
    const float* b2 = (const float*)d_in[6];
    float* out = (float*)d_out;

    char* ws = (char*)d_ws;
    size_t off = 0;
    auto alloc = [&](size_t bytes) {
        char* p = ws + off;
        off += (bytes + 255) & ~(size_t)255;
        return p;
    };
    unsigned short* w1t  = (unsigned short*)alloc((size_t)NE * F_DIM * H_DIM * 2);  // 67 MB
    unsigned short* w2t  = (unsigned short*)alloc((size_t)NE * H_DIM * F_DIM * 2);  // 67 MB
    unsigned short* xb   = (unsigned short*)alloc((size_t)T_TOK * H_DIM * 2);       // 17 MB
    unsigned short* hbuf = (unsigned short*)alloc((size_t)(T_TOK * 2 + NE * 128) * F_DIM * 2); // 143 MB
    int*   cnt  = (int*)alloc(NE * 4);
    int*   offs = (int*)alloc((NE + 1) * 4);
    int*   perm = (int*)alloc((size_t)NE * CAP * 4);
    float* pw   = (float*)alloc((size_t)NE * CAP * 4);
    (void)ws_size; (void)in_sizes; (void)n_in; (void)out_size;

    hipMemsetAsync(cnt, 0, NE * 4, stream);
    router_k<<<T_TOK / 4, 256, 0, stream>>>(x, Wr, br, cnt, perm, pw);
    prefix_k<<<1, 64, 0, stream>>>(cnt, offs);
    tcvt_k<<<dim3(F_DIM / 64, H_DIM / 64, NE), 256, 0, stream>>>(W1, w1t, H_DIM, F_DIM);
    tcvt_k<<<dim3(H_DIM / 64, F_DIM / 64, NE), 256, 0, stream>>>(W2, w2t, F_DIM, H_DIM);
    xcvt_k<<<(T_TOK * H_DIM) / 2048, 256, 0, stream>>>(x, xb);
    gemm1_k<<<dim3(F_DIM / 128, MBLK_MAX, NE), 256, 0, stream>>>(xb, w1t, b1, hbuf, perm, cnt, offs);
    hipMemsetAsync(out, 0, (size_t)T_TOK * H_DIM * 4, stream);
    gemm2_k<<<dim3(H_DIM / 128, MBLK_MAX, NE), 256, 0, stream>>>(hbuf, w2t, b2, out, perm, pw, cnt, offs);
}

// Round 2
// 803.436 us; speedup vs baseline: 1.4646x; 1.4646x over previous
//
#include <hip/hip_runtime.h>
#include <cstdint>
#include <cmath>

#define T_TOK 8192
#define H_DIM 1024
#define F_DIM 4096
#define NE 8
#define CAP 8192        // perm capacity per expert
#define MBLK_MAX 32     // max M-blocks per expert (4096-token cap; >50 sigma above mean 2048)
#define BK 64

typedef __attribute__((ext_vector_type(8))) short short8v;
typedef __attribute__((ext_vector_type(4))) float f32x4;

static __device__ __forceinline__ unsigned short f2bf(float f) {
    union { float f; unsigned int u; } v; v.f = f;
    unsigned int r = v.u + 0x7FFFu + ((v.u >> 16) & 1u);  // RNE
    return (unsigned short)(r >> 16);
}

// async global->LDS, 16B per lane; LDS dest is wave-uniform base + lane*16,
// global src is per-lane (supports gather + pre-swizzled source).
static __device__ __forceinline__ void gl_lds16(const void* g, void* l) {
    __builtin_amdgcn_global_load_lds(
        (const __attribute__((address_space(1))) unsigned int*)g,
        (__attribute__((address_space(3))) unsigned int*)l, 16, 0, 0);
}

// ---------------- router: logits, top-2, weights, per-expert compaction ----------------
__global__ void router_k(const float* __restrict__ x, const float* __restrict__ Wr,
                         const float* __restrict__ br,
                         int* __restrict__ cnt, int* __restrict__ perm, float* __restrict__ pw)
{
    const int wave = threadIdx.x >> 6;
    const int lane = threadIdx.x & 63;
    const int t = blockIdx.x * 4 + wave;
    const float* xr = x + (size_t)t * H_DIM;
    float acc[NE];
#pragma unroll
    for (int e = 0; e < NE; ++e) acc[e] = 0.f;
#pragma unroll
    for (int c0 = 0; c0 < H_DIM; c0 += 256) {
        const float4 v = *(const float4*)(xr + c0 + lane * 4);
        const int hbase = c0 + lane * 4;
        float vv[4] = {v.x, v.y, v.z, v.w};
#pragma unroll
        for (int i = 0; i < 4; ++i) {
            const float4 w0 = *(const float4*)(Wr + (size_t)(hbase + i) * NE);
            const float4 w1 = *(const float4*)(Wr + (size_t)(hbase + i) * NE + 4);
            acc[0] += vv[i] * w0.x; acc[1] += vv[i] * w0.y;
            acc[2] += vv[i] * w0.z; acc[3] += vv[i] * w0.w;
            acc[4] += vv[i] * w1.x; acc[5] += vv[i] * w1.y;
            acc[6] += vv[i] * w1.z; acc[7] += vv[i] * w1.w;
        }
    }
#pragma unroll
    for (int off = 32; off > 0; off >>= 1) {
#pragma unroll
        for (int e = 0; e < NE; ++e) acc[e] += __shfl_xor(acc[e], off, 64);
    }
    if (lane == 0) {
#pragma unroll
        for (int e = 0; e < NE; ++e) acc[e] += br[e];
        int i0 = 0; float l0 = acc[0];
#pragma unroll
        for (int e = 1; e < NE; ++e) if (acc[e] > l0) { l0 = acc[e]; i0 = e; }
        int i1 = -1; float l1 = -3.4e38f;
#pragma unroll
        for (int e = 0; e < NE; ++e) if (e != i0 && acc[e] > l1) { l1 = acc[e]; i1 = e; }
        // top-2 renormalized softmax weights from logits (exact)
        const float w0 = 1.f / (1.f + expf(l1 - l0));
        const int p0 = atomicAdd(&cnt[i0], 1);
        perm[i0 * CAP + p0] = t; pw[i0 * CAP + p0] = w0;
        const int p1 = atomicAdd(&cnt[i1], 1);
        perm[i1 * CAP + p1] = t; pw[i1 * CAP + p1] = 1.f - w0;
    }
}

// ---------------- 128-aligned exclusive prefix of counts ----------------
__global__ void prefix_k(const int* __restrict__ cnt, int* __restrict__ offs)
{
    if (threadIdx.x == 0 && blockIdx.x == 0) {
        int o = 0;
        for (int e = 0; e < NE; ++e) { offs[e] = o; o += ((cnt[e] + 127) >> 7) << 7; }
        offs[NE] = o;
    }
}

// ---------------- transpose + fp32->bf16 convert: in[E][R][C] -> out[E][C][R] ----------------
__global__ __launch_bounds__(256) void tcvt_k(const float* __restrict__ in,
                                              unsigned short* __restrict__ out,
                                              int R, int C)
{
    __shared__ float tile[64][65];
    const int e = blockIdx.z;
    const int r0 = blockIdx.y * 64, c0 = blockIdx.x * 64;
    const float* ip = in + (size_t)e * R * C;
    unsigned short* op = out + (size_t)e * R * C;
    const int j = threadIdx.x;
    const int lr = j >> 4, lc = (j & 15) * 4;
#pragma unroll
    for (int p = 0; p < 4; ++p) {
        const float4 v = *(const float4*)(ip + (size_t)(r0 + lr + p * 16) * C + c0 + lc);
        tile[lr + p * 16][lc + 0] = v.x;
        tile[lr + p * 16][lc + 1] = v.y;
        tile[lr + p * 16][lc + 2] = v.z;
        tile[lr + p * 16][lc + 3] = v.w;
    }
    __syncthreads();
#pragma unroll
    for (int p = 0; p < 4; ++p) {
        const int orow = lr + p * 16;
        ushort4 o;
        o.x = f2bf(tile[lc + 0][orow]);
        o.y = f2bf(tile[lc + 1][orow]);
        o.z = f2bf(tile[lc + 2][orow]);
        o.w = f2bf(tile[lc + 3][orow]);
        *(ushort4*)(op + (size_t)(c0 + orow) * R + r0 + lc) = o;
    }
}

// ---------------- x fp32 -> bf16 ----------------
__global__ __launch_bounds__(256) void xcvt_k(const float* __restrict__ x,
                                              unsigned short* __restrict__ xb)
{
    const size_t i = ((size_t)blockIdx.x * 256 + threadIdx.x) * 8;
    const float4 a = *(const float4*)(x + i);
    const float4 b = *(const float4*)(x + i + 4);
    uint4 o;
    o.x = f2bf(a.x) | ((unsigned)f2bf(a.y) << 16);
    o.y = f2bf(a.z) | ((unsigned)f2bf(a.w) << 16);
    o.z = f2bf(b.x) | ((unsigned)f2bf(b.y) << 16);
    o.w = f2bf(b.z) | ((unsigned)f2bf(b.w) << 16);
    *(uint4*)(xb + i) = o;
}

// ---------------- GEMM1: h = gelu(gather(x) @ W1[e] + b1[e]), bf16 out ----------------
// 128x128 tile, BK=64, global_load_lds direct staging, XOR-swizzled source+read.
__global__ __launch_bounds__(256, 2) void gemm1_k(
    const unsigned short* __restrict__ xb,   // [T][H] bf16
    const unsigned short* __restrict__ w1t,  // [E][F][H] bf16 (pre-transposed)
    const float* __restrict__ b1,            // [E][F]
    unsigned short* __restrict__ hbuf,       // [rows][F] bf16
    const int* __restrict__ perm, const int* __restrict__ cnt, const int* __restrict__ offs)
{
    __shared__ __align__(16) unsigned short lA[128 * BK];
    __shared__ __align__(16) unsigned short lB[128 * BK];
    __shared__ int rows_s[128];

    constexpr int NY = F_DIM / 128;            // 32
    constexpr int nwg = MBLK_MAX * NY * NE;    // 8192, divisible by 8
    const int bid = blockIdx.x;
    const int wg = (bid & 7) * (nwg >> 3) + (bid >> 3);   // XCD-aware bijective swizzle
    const int e  = wg / (MBLK_MAX * NY);
    const int rem = wg % (MBLK_MAX * NY);
    const int nb = rem / MBLK_MAX;
    const int mb = rem % MBLK_MAX;             // fastest -> same-XCD neighbors share B panel

    const int c = cnt[e];
    const int m0 = mb * 128;
    if (m0 >= c) return;
    const int tid = threadIdx.x;

    if (tid < 128) {
        const int i = m0 + tid;
        rows_s[tid] = perm[e * CAP + (i < c ? i : c - 1)];
    }
    __syncthreads();

    const int lane = tid & 63;
    const int w = tid >> 6;            // wave 0..3 (stages rows [w*32, w*32+32))
    const int lr8 = lane >> 3;         // row-within-8
    const int u = lane & 7;            // 16B unit within 128B row

    const unsigned short* bp = w1t + ((size_t)e * F_DIM + nb * 128) * H_DIM;
    const unsigned short* srcA[4];
    const unsigned short* srcB[4];
    unsigned short* dstA[4];
    unsigned short* dstB[4];
#pragma unroll
    for (int j = 0; j < 4; ++j) {
        const int r = w * 32 + j * 8 + lr8;
        const int us = (u ^ (r & 7)) * 8;      // pre-swizzled source unit
        srcA[j] = xb + (size_t)rows_s[r] * H_DIM + us;
        srcB[j] = bp + (size_t)r * H_DIM + us;
        dstA[j] = lA + (w * 32 + j * 8) * BK;  // wave-uniform LDS base
        dstB[j] = lB + (w * 32 + j * 8) * BK;
    }

    f32x4 acc[4][4];
#pragma unroll
    for (int m = 0; m < 4; ++m)
#pragma unroll
        for (int n = 0; n < 4; ++n) acc[m][n] = (f32x4){0.f, 0.f, 0.f, 0.f};

    const int wr = (tid >> 7) & 1;
    const int wc = (tid >> 6) & 1;
    const int fr = lane & 15;
    const int fg = lane >> 4;
    const int fx = fr & 7;

    for (int k0 = 0; k0 < H_DIM; k0 += BK) {
#pragma unroll
        for (int j = 0; j < 4; ++j) gl_lds16(srcA[j] + k0, dstA[j]);
#pragma unroll
        for (int j = 0; j < 4; ++j) gl_lds16(srcB[j] + k0, dstB[j]);
        __syncthreads();   // drains vmcnt (global_load_lds) + barrier
#pragma unroll
        for (int kk = 0; kk < 2; ++kk) {
            const int ua = ((fg + kk * 4) ^ fx) * 8;   // swizzled read unit
            short8v a[4], b[4];
#pragma unroll
            for (int m = 0; m < 4; ++m)
                a[m] = *(const short8v*)(lA + (wr * 64 + m * 16 + fr) * BK + ua);
#pragma unroll
            for (int n = 0; n < 4; ++n)
                b[n] = *(const short8v*)(lB + (wc * 64 + n * 16 + fr) * BK + ua);
#pragma unroll
            for (int m = 0; m < 4; ++m)
#pragma unroll
                for (int n = 0; n < 4; ++n)
                    acc[m][n] = __builtin_amdgcn_mfma_f32_16x16x32_bf16(a[m], b[n], acc[m][n], 0, 0, 0);
        }
        __syncthreads();
    }

    const size_t hrow0 = (size_t)offs[e] + m0;
#pragma unroll
    for (int n = 0; n < 4; ++n) {
        const int gc = nb * 128 + wc * 64 + n * 16 + fr;
        const float bias = b1[e * F_DIM + gc];
#pragma unroll
        for (int m = 0; m < 4; ++m) {
#pragma unroll
            for (int r = 0; r < 4; ++r) {
                const int lr2 = wr * 64 + m * 16 + fg * 4 + r;
                const float xv = acc[m][n][r] + bias;
                const float g = 0.5f * xv * (1.f + erff(xv * 0.70710678118f));
                hbuf[(hrow0 + lr2) * F_DIM + gc] = f2bf(g);
            }
        }
    }
}

// ---------------- GEMM2: out[t] += w * (h @ W2[e] + b2[e]) ----------------
__global__ __launch_bounds__(256, 2) void gemm2_k(
    const unsigned short* __restrict__ hbuf, // [rows][F] bf16
    const unsigned short* __restrict__ w2t,  // [E][H][F] bf16 (pre-transposed)
    const float* __restrict__ b2,            // [E][H]
    float* __restrict__ out,                 // [T][H] fp32 (pre-zeroed)
    const int* __restrict__ perm, const float* __restrict__ pw,
    const int* __restrict__ cnt, const int* __restrict__ offs)
{
    __shared__ __align__(16) unsigned short lA[128 * BK];
    __shared__ __align__(16) unsigned short lB[128 * BK];
    __shared__ int rows_s[128];
    __shared__ float pw_s[128];

    constexpr int NY = H_DIM / 128;            // 8
    constexpr int nwg = MBLK_MAX * NY * NE;    // 2048, divisible by 8
    const int bid = blockIdx.x;
    const int wg = (bid & 7) * (nwg >> 3) + (bid >> 3);
    const int e  = wg / (MBLK_MAX * NY);
    const int rem = wg % (MBLK_MAX * NY);
    const int nb = rem / MBLK_MAX;
    const int mb = rem % MBLK_MAX;

    const int c = cnt[e];
    const int m0 = mb * 128;
    if (m0 >= c) return;
    const int tid = threadIdx.x;

    if (tid < 128) {
        const int i = m0 + tid;
        const int ic = (i < c ? i : c - 1);
        rows_s[tid] = perm[e * CAP + ic];
        pw_s[tid]   = pw[e * CAP + ic];
    }
    __syncthreads();

    const int lane = tid & 63;
    const int w = tid >> 6;
    const int lr8 = lane >> 3;
    const int u = lane & 7;

    const size_t arow0 = (size_t)offs[e] + m0;
    const unsigned short* bp = w2t + ((size_t)e * H_DIM + nb * 128) * F_DIM;
    const unsigned short* srcA[4];
    const unsigned short* srcB[4];
    unsigned short* dstA[4];
    unsigned short* dstB[4];
#pragma unroll
    for (int j = 0; j < 4; ++j) {
        const int r = w * 32 + j * 8 + lr8;
        const int us = (u ^ (r & 7)) * 8;
        srcA[j] = hbuf + (arow0 + r) * F_DIM + us;
        srcB[j] = bp + (size_t)r * F_DIM + us;
        dstA[j] = lA + (w * 32 + j * 8) * BK;
        dstB[j] = lB + (w * 32 + j * 8) * BK;
    }

    f32x4 acc[4][4];
#pragma unroll
    for (int m = 0; m < 4; ++m)
#pragma unroll
        for (int n = 0; n < 4; ++n) acc[m][n] = (f32x4){0.f, 0.f, 0.f, 0.f};

    const int wr = (tid >> 7) & 1;
    const int wc = (tid >> 6) & 1;
    const int fr = lane & 15;
    const int fg = lane >> 4;
    const int fx = fr & 7;

    for (int k0 = 0; k0 < F_DIM; k0 += BK) {
#pragma unroll
        for (int j = 0; j < 4; ++j) gl_lds16(srcA[j] + k0, dstA[j]);
#pragma unroll
        for (int j = 0; j < 4; ++j) gl_lds16(srcB[j] + k0, dstB[j]);
        __syncthreads();
#pragma unroll
        for (int kk = 0; kk < 2; ++kk) {
            const int ua = ((fg + kk * 4) ^ fx) * 8;
            short8v a[4], b[4];
#pragma unroll
            for (int m = 0; m < 4; ++m)
                a[m] = *(const short8v*)(lA + (wr * 64 + m * 16 + fr) * BK + ua);
#pragma unroll
            for (int n = 0; n < 4; ++n)
                b[n] = *(const short8v*)(lB + (wc * 64 + n * 16 + fr) * BK + ua);
#pragma unroll
            for (int m = 0; m < 4; ++m)
#pragma unroll
                for (int n = 0; n < 4; ++n)
                    acc[m][n] = __builtin_amdgcn_mfma_f32_16x16x32_bf16(a[m], b[n], acc[m][n], 0, 0, 0);
        }
        __syncthreads();
    }

#pragma unroll
    for (int n = 0; n < 4; ++n) {
        const int gc = nb * 128 + wc * 64 + n * 16 + fr;
        const float bias = b2[e * H_DIM + gc];
#pragma unroll
        for (int m = 0; m < 4; ++m) {
#pragma unroll
            for (int r = 0; r < 4; ++r) {
                const int lr2 = wr * 64 + m * 16 + fg * 4 + r;
                if (m0 + lr2 < c) {
                    const float y = acc[m][n][r] + bias;
                    atomicAdd(out + (size_t)rows_s[lr2] * H_DIM + gc, pw_s[lr2] * y);
                }
            }
        }
    }
}

extern "C" void kernel_launch(void* const* d_in, const int* in_sizes, int n_in,
                              void* d_out, int out_size, void* d_ws, size_t ws_size,
                              hipStream_t stream)
{
    const float* x  = (const float*)d_in[0];
    const float* Wr = (const float*)d_in[1];
    const float* br = (const float*)d_in[2];
    const float* W1 = (const float*)d_in[3];
    const float* b1 = (const float*)d_in[4];
    const float* W2 = (const float*)d_in[5];
    const float* b2 = (const float*)d_in[6];
    float* out = (float*)d_out;

    char* ws = (char*)d_ws;
    size_t off = 0;
    auto alloc = [&](size_t bytes) {
        char* p = ws + off;
        off += (bytes + 255) & ~(size_t)255;
        return p;
    };
    unsigned short* w1t  = (unsigned short*)alloc((size_t)NE * F_DIM * H_DIM * 2);  // 67 MB
    unsigned short* w2t  = (unsigned short*)alloc((size_t)NE * H_DIM * F_DIM * 2);  // 67 MB
    unsigned short* xb   = (unsigned short*)alloc((size_t)T_TOK * H_DIM * 2);       // 17 MB
    unsigned short* hbuf = (unsigned short*)alloc((size_t)(T_TOK * 2 + NE * 128) * F_DIM * 2); // 143 MB
    int*   cnt  = (int*)alloc(NE * 4);
    int*   offs = (int*)alloc((NE + 1) * 4);
    int*   perm = (int*)alloc((size_t)NE * CAP * 4);
    float* pw   = (float*)alloc((size_t)NE * CAP * 4);
    (void)ws_size; (void)in_sizes; (void)n_in; (void)out_size;

    hipMemsetAsync(cnt, 0, NE * 4, stream);
    router_k<<<T_TOK / 4, 256, 0, stream>>>(x, Wr, br, cnt, perm, pw);
    prefix_k<<<1, 64, 0, stream>>>(cnt, offs);
    tcvt_k<<<dim3(F_DIM / 64, H_DIM / 64, NE), 256, 0, stream>>>(W1, w1t, H_DIM, F_DIM);
    tcvt_k<<<dim3(H_DIM / 64, F_DIM / 64, NE), 256, 0, stream>>>(W2, w2t, F_DIM, H_DIM);
    xcvt_k<<<(T_TOK * H_DIM) / 2048, 256, 0, stream>>>(x, xb);
    gemm1_k<<<MBLK_MAX * (F_DIM / 128) * NE, 256, 0, stream>>>(xb, w1t, b1, hbuf, perm, cnt, offs);
    hipMemsetAsync(out, 0, (size_t)T_TOK * H_DIM * 4, stream);
    gemm2_k<<<MBLK_MAX * (H_DIM / 128) * NE, 256, 0, stream>>>(hbuf, w2t, b2, out, perm, pw, cnt, offs);
}